// Round 24
// baseline (98.347 us; speedup 1.0000x reference)
//
#include <hip/hip_runtime.h>
#include <stdint.h>

#define CLASS_NUM 7
#define QROWS 1050
#define QPAD  1152              // 72 groups * 16 rows; pad rows are zero
#define NPAD  102               // pad rows each add exp2(0)=1 to denom
#define NGRP  72
#define GPW   18                // groups per wave (one queue quarter)
#define QSUM_OFF (QPAD * 128)   // 147456: 7x128 fp32 class sums (after fp8 image)
#define PART_OFF 151552         // 1024 fp32 per-block partials
#define CNT_OFF  155648         // completion counter (zeroed by prep_q8)
#define NBLK  1024
#define C2L 2.8853900817779268f // 2/ln2 : exp(2s) = exp2(s*C2L)
#define USCALE 0x7F7F7F7F       // unit E8M0 scales (127 -> 2^0)

typedef float f32x4 __attribute__((ext_vector_type(4)));
typedef int   i32x8 __attribute__((ext_vector_type(8)));

__device__ __forceinline__ float fexp2(float x) { return __builtin_amdgcn_exp2f(x); }

// pack 4 floats -> 4 fp8 e4m3 (OCP, RNE) in one dword
__device__ __forceinline__ unsigned pk8(float a, float b, float c, float d) {
  int v = __builtin_amdgcn_cvt_pk_fp8_f32(a, b, 0, false);
  v = __builtin_amdgcn_cvt_pk_fp8_f32(c, d, v, true);
  return (unsigned)v;
}

// ---- prep: blocks 0-71 -> fp8 K=128-fragment queue image; blocks 72-78 ->
// per-class column sums; block 0 zeroes the completion counter (replay-safe).
__global__ __launch_bounds__(256) void prep_q8(
    const float* __restrict__ queue, char* __restrict__ ws)
{
  const int b = blockIdx.x, tid = threadIdx.x;
  if (b == 0 && tid == 0) *(unsigned*)(ws + CNT_OFF) = 0u;
  if (b < NGRP) {
    const int g = b;
    const int lane = tid >> 2, k = tid & 3;
    const int row = g * 16 + (lane & 15);
    const int col = (lane >> 4) * 32 + k * 8;   // MX layout: contiguous 32/lane
    uint2 u = {0u, 0u};
    if (row < QROWS) {
      const float4 v0 = *(const float4*)(queue + row * 128 + col);
      const float4 v1 = *(const float4*)(queue + row * 128 + col + 4);
      u.x = pk8(v0.x, v0.y, v0.z, v0.w);
      u.y = pk8(v1.x, v1.y, v1.z, v1.w);
    }
    *(uint2*)(ws + (size_t)g * 2048 + tid * 8) = u;
  } else if (tid < 128) {
    const int c = b - NGRP, d = tid;
    float s = 0.f;
    const float* p = queue + c * 150 * 128 + d;
#pragma unroll 10
    for (int i = 0; i < 150; ++i) s += p[i * 128];
    ((float*)(ws + QSUM_OFF))[c * 128 + d] = s;
  }
}

// ---- fused main (R22 winner + group rotation + fused finalize):
// 1024 blocks x 256 thr (4 waves), 64 B-rows/block, MX K=128 sweep.
// Each block starts its quarter-sweep at group (blockIdx % 18) to
// de-correlate L2 hot-line access across the chip's waves.
__global__ __launch_bounds__(256, 2) void pgc_stream(
    const float* __restrict__ act, const float* __restrict__ ema,
    const float* __restrict__ plab, char* __restrict__ ws,
    float* __restrict__ out)
{
  __shared__ __align__(16) char aT[8192];    // 64-row fp8 A tile, K=128 frags
  __shared__ float s_lpos[64], s_pd[64];
  __shared__ float dnp[4][64];
  __shared__ int s_last;

  const int tid = threadIdx.x, lane = tid & 63, wave = tid >> 6;
  const int lo = lane & 15, hi = lane >> 4;

  // ---- prologue: 4 threads/row, 64 rows. All independent loads up-front.
  {
    const int r = tid >> 2, j4 = tid & 3;
    const long grow = (long)blockIdx.x * 64 + r;
    const float* ap = act + grow * 128 + j4 * 32;
    const float* ep = ema + grow * 128 + j4 * 32;

    float pv0 = plab[grow * CLASS_NUM + j4];
    float pv1 = (j4 + 4 < CLASS_NUM) ? plab[grow * CLASS_NUM + j4 + 4] : -3.4e38f;
    f32x4 a4[8], e4[8];
#pragma unroll
    for (int u = 0; u < 8; ++u) a4[u] = *(const f32x4*)(ap + 4 * u);
#pragma unroll
    for (int u = 0; u < 8; ++u) e4[u] = *(const f32x4*)(ep + 4 * u);

    float a2 = 0.f, e2 = 0.f, ae = 0.f;
#pragma unroll
    for (int u = 0; u < 8; ++u) {
      a2 += a4[u].x*a4[u].x + a4[u].y*a4[u].y + a4[u].z*a4[u].z + a4[u].w*a4[u].w;
      e2 += e4[u].x*e4[u].x + e4[u].y*e4[u].y + e4[u].z*e4[u].z + e4[u].w*e4[u].w;
      ae += a4[u].x*e4[u].x + a4[u].y*e4[u].y + a4[u].z*e4[u].z + a4[u].w*e4[u].w;
    }
#pragma unroll
    for (int m = 1; m < 4; m <<= 1) {
      a2 += __shfl_xor(a2, m);
      e2 += __shfl_xor(e2, m);
      ae += __shfl_xor(ae, m);
    }
    const float rna = rsqrtf(a2), rne = rsqrtf(e2);

    // argmax over 7 classes: 2 classes/thread then 4-lane first-max vote
    float pv = pv0; int bi = j4;
    if (pv1 > pv0) { pv = pv1; bi = j4 + 4; }
#pragma unroll
    for (int m = 1; m < 4; m <<= 1) {
      const float ov = __shfl_xor(pv, m);
      const int   oi = __shfl_xor(bi, m);
      if (ov > pv || (ov == pv && oi < bi)) { pv = ov; bi = oi; }
    }

    // positive-sum via precomputed class sums (fp32-exact)
    const float* qs = (const float*)(ws + QSUM_OFF) + bi * 128 + j4 * 32;
    float pdot = 0.f;
#pragma unroll
    for (int u = 0; u < 8; ++u) {
      const float4 qv = *(const float4*)(qs + 4 * u);
      pdot += a4[u].x*qv.x + a4[u].y*qv.y + a4[u].z*qv.z + a4[u].w*qv.w;
    }
#pragma unroll
    for (int m = 1; m < 4; m <<= 1) pdot += __shfl_xor(pdot, m);

    if (j4 == 0) {
      s_lpos[r] = ae * rna * rne * C2L;
      s_pd[r]   = pdot * rna;
    }

    // stage A in MX frag layout: set st = r>>4, target lane tl = j4*16 + (r&15)
    const float sc = rna * C2L;     // pre-scale so MFMA output is 2s/ln2
    const int st = r >> 4, tl = j4 * 16 + (r & 15);
    uint4 w0, w1;
    w0.x = pk8(a4[0].x*sc, a4[0].y*sc, a4[0].z*sc, a4[0].w*sc);
    w0.y = pk8(a4[1].x*sc, a4[1].y*sc, a4[1].z*sc, a4[1].w*sc);
    w0.z = pk8(a4[2].x*sc, a4[2].y*sc, a4[2].z*sc, a4[2].w*sc);
    w0.w = pk8(a4[3].x*sc, a4[3].y*sc, a4[3].z*sc, a4[3].w*sc);
    w1.x = pk8(a4[4].x*sc, a4[4].y*sc, a4[4].z*sc, a4[4].w*sc);
    w1.y = pk8(a4[5].x*sc, a4[5].y*sc, a4[5].z*sc, a4[5].w*sc);
    w1.z = pk8(a4[6].x*sc, a4[6].y*sc, a4[6].z*sc, a4[6].w*sc);
    w1.w = pk8(a4[7].x*sc, a4[7].y*sc, a4[7].z*sc, a4[7].w*sc);
    *(uint4*)(aT + st * 2048 + tl * 32)      = w0;
    *(uint4*)(aT + st * 2048 + tl * 32 + 16) = w1;
  }
  __syncthreads();

  // A fragments: 4 sets (64 rows) per wave, 32 B/lane each (K=128 operand)
  i32x8 sa[4];
#pragma unroll
  for (int s = 0; s < 4; ++s)
    sa[s] = *(const i32x8*)(aT + s * 2048 + lane * 32);

  float dn[4][4] = {{0.f,0.f,0.f,0.f},{0.f,0.f,0.f,0.f},
                    {0.f,0.f,0.f,0.f},{0.f,0.f,0.f,0.f}};
  const f32x4 Z = {0.f, 0.f, 0.f, 0.f};
  const char* qp = ws + (size_t)(wave * GPW) * 2048 + (size_t)lane * 32;
  const int base = blockIdx.x % GPW;     // per-block rotation (hot-line spread)

  i32x8 B0, B1, B2;
#define LOADG(X, G)                                                     \
  { int gi_ = (G) + base; if (gi_ >= GPW) gi_ -= GPW;                   \
    X = *(const i32x8*)(qp + gi_ * 2048); }
#define COMPG(X)                                                        \
  { _Pragma("unroll")                                                   \
    for (int s = 0; s < 4; ++s) {                                       \
      f32x4 c = __builtin_amdgcn_mfma_scale_f32_16x16x128_f8f6f4(       \
          sa[s], X, Z, 0, 0, 0, USCALE, 0, USCALE);                     \
      _Pragma("unroll")                                                 \
      for (int rg = 0; rg < 4; ++rg) dn[s][rg] += fexp2(c[rg]);         \
    } }

  LOADG(B0, 0)
  LOADG(B1, 1)
  LOADG(B2, 2)
#pragma unroll 1
  for (int g = 0; g < GPW - 3; g += 3) {
    COMPG(B0) LOADG(B0, g + 3)
    COMPG(B1) LOADG(B1, g + 4)
    COMPG(B2) LOADG(B2, g + 5)
  }
  COMPG(B0)
  COMPG(B1)
  COMPG(B2)
#undef LOADG
#undef COMPG

  // reduce across the 16 q-column lanes of each row
#pragma unroll
  for (int s = 0; s < 4; ++s)
#pragma unroll
    for (int rg = 0; rg < 4; ++rg)
#pragma unroll
      for (int m = 1; m < 16; m <<= 1)
        dn[s][rg] += __shfl_xor(dn[s][rg], m);

  if (lo == 0) {
#pragma unroll
    for (int s = 0; s < 4; ++s)
#pragma unroll
      for (int rg = 0; rg < 4; ++rg)
        dnp[wave][s * 16 + hi * 4 + rg] = dn[s][rg];
  }
  __syncthreads();

  // epilogue: thread i (< 64) owns block-row i; partial -> plain store
  if (tid < 64) {
    const int i = tid;
    const float dtot = dnp[0][i] + dnp[1][i] + dnp[2][i] + dnp[3][i];
    const float lp   = exp2f(s_lpos[i]);        // exp(2*<f,ema_f>)
    const float dnf  = lp + dtot - (float)NPAD;
    float loss = -logf(lp / dnf + 1e-8f) + 150.0f * logf(dnf) - 2.0f * s_pd[i];
#pragma unroll
    for (int m = 1; m < 64; m <<= 1) loss += __shfl_xor(loss, m);
    if (tid == 0)
      ((float*)(ws + PART_OFF))[blockIdx.x] = loss;
  }

  // ---- fused finalize: last-done block reduces the 1024 partials.
  __threadfence();
  if (tid == 0) {
    const unsigned old = atomicAdd((unsigned*)(ws + CNT_OFF), 1u);
    s_last = (old == NBLK - 1u) ? 1 : 0;
  }
  __syncthreads();
  if (s_last) {
    __threadfence();   // acquire: see all blocks' partial stores
    const float* parts = (const float*)(ws + PART_OFF);
    float v = parts[tid] + parts[tid + 256] + parts[tid + 512] + parts[tid + 768];
#pragma unroll
    for (int m = 1; m < 64; m <<= 1) v += __shfl_xor(v, m);
    if (lane == 0) dnp[0][wave] = v;   // dnp free post-barrier
    __syncthreads();
    if (tid == 0)
      *out = (dnp[0][0] + dnp[0][1] + dnp[0][2] + dnp[0][3]) *
             (1.0f / (151.0f * 65536.0f));
  }
}

extern "C" void kernel_launch(void* const* d_in, const int* in_sizes, int n_in,
                              void* d_out, int out_size, void* d_ws, size_t ws_size,
                              hipStream_t stream) {
  const float* act   = (const float*)d_in[0];
  const float* ema   = (const float*)d_in[1];
  const float* plab  = (const float*)d_in[2];
  const float* queue = (const float*)d_in[3];
  float* out = (float*)d_out;

  prep_q8<<<dim3(NGRP + CLASS_NUM), dim3(256), 0, stream>>>(queue, (char*)d_ws);

  pgc_stream<<<dim3(NBLK), dim3(256), 0, stream>>>(
      act, ema, plab, (char*)d_ws, out);
}

// Round 25
// 37.890 us; speedup vs baseline: 2.5956x; 2.5956x over previous
//
#include <hip/hip_runtime.h>
#include <stdint.h>

#define CLASS_NUM 7
#define QROWS 1050
#define QPAD  1152              // 72 groups * 16 rows; pad rows are zero
#define NPAD  102               // pad rows each add exp2(0)=1 to denom
#define NGRP  72
#define GPW   18                // groups per wave (one queue quarter)
#define QSUM_OFF (QPAD * 128)   // 147456: 7x128 fp32 class sums (after fp8 image)
#define PART_OFF 151552         // per-block partials
#define NBLK  1024
#define C2L 2.8853900817779268f // 2/ln2 : exp(2s) = exp2(s*C2L)
#define USCALE 0x7F7F7F7F       // unit E8M0 scales (127 -> 2^0)

typedef float f32x4 __attribute__((ext_vector_type(4)));
typedef int   i32x8 __attribute__((ext_vector_type(8)));

__device__ __forceinline__ float fexp2(float x) { return __builtin_amdgcn_exp2f(x); }

// pack 4 floats -> 4 fp8 e4m3 (OCP, RNE) in one dword
__device__ __forceinline__ unsigned pk8(float a, float b, float c, float d) {
  int v = __builtin_amdgcn_cvt_pk_fp8_f32(a, b, 0, false);
  v = __builtin_amdgcn_cvt_pk_fp8_f32(c, d, v, true);
  return (unsigned)v;
}

// ---- prep (single dispatch): blocks 0-71 -> fp8 K=128-fragment queue image
// (lane l of group g holds Q[g*16+(l&15)][(l>>4)*32 .. +32]); blocks 72-78 ->
// per-class column sums.  (verified)
__global__ __launch_bounds__(256) void prep_q8(
    const float* __restrict__ queue, char* __restrict__ ws)
{
  const int b = blockIdx.x, tid = threadIdx.x;
  if (b < NGRP) {
    const int g = b;
    const int lane = tid >> 2, k = tid & 3;
    const int row = g * 16 + (lane & 15);
    const int col = (lane >> 4) * 32 + k * 8;   // MX layout: contiguous 32/lane
    uint2 u = {0u, 0u};
    if (row < QROWS) {
      const float4 v0 = *(const float4*)(queue + row * 128 + col);
      const float4 v1 = *(const float4*)(queue + row * 128 + col + 4);
      u.x = pk8(v0.x, v0.y, v0.z, v0.w);
      u.y = pk8(v1.x, v1.y, v1.z, v1.w);
    }
    *(uint2*)(ws + (size_t)g * 2048 + tid * 8) = u;
  } else if (tid < 128) {
    const int c = b - NGRP, d = tid;
    float s = 0.f;
    const float* p = queue + c * 150 * 128 + d;
#pragma unroll 10
    for (int i = 0; i < 150; ++i) s += p[i * 128];
    ((float*)(ws + QSUM_OFF))[c * 128 + d] = s;
  }
}

// ---- fused main: EXACT R22 kernel (verified 38.5 total) with ONE delta:
// per-block sweep-start rotation (base = blockIdx % 18) to de-correlate
// which queue lines the chip's waves hit at any instant.
__global__ __launch_bounds__(256, 2) void pgc_stream(
    const float* __restrict__ act, const float* __restrict__ ema,
    const float* __restrict__ plab, char* __restrict__ ws)
{
  __shared__ __align__(16) char aT[8192];    // 64-row fp8 A tile, K=128 frags
  __shared__ float s_lpos[64], s_pd[64];
  __shared__ float dnp[4][64];

  const int tid = threadIdx.x, lane = tid & 63, wave = tid >> 6;
  const int lo = lane & 15, hi = lane >> 4;

  // ---- prologue: 4 threads/row, 64 rows. All independent loads up-front.
  {
    const int r = tid >> 2, j4 = tid & 3;
    const long grow = (long)blockIdx.x * 64 + r;
    const float* ap = act + grow * 128 + j4 * 32;
    const float* ep = ema + grow * 128 + j4 * 32;

    float pv0 = plab[grow * CLASS_NUM + j4];
    float pv1 = (j4 + 4 < CLASS_NUM) ? plab[grow * CLASS_NUM + j4 + 4] : -3.4e38f;
    f32x4 a4[8], e4[8];
#pragma unroll
    for (int u = 0; u < 8; ++u) a4[u] = *(const f32x4*)(ap + 4 * u);
#pragma unroll
    for (int u = 0; u < 8; ++u) e4[u] = *(const f32x4*)(ep + 4 * u);

    float a2 = 0.f, e2 = 0.f, ae = 0.f;
#pragma unroll
    for (int u = 0; u < 8; ++u) {
      a2 += a4[u].x*a4[u].x + a4[u].y*a4[u].y + a4[u].z*a4[u].z + a4[u].w*a4[u].w;
      e2 += e4[u].x*e4[u].x + e4[u].y*e4[u].y + e4[u].z*e4[u].z + e4[u].w*e4[u].w;
      ae += a4[u].x*e4[u].x + a4[u].y*e4[u].y + a4[u].z*e4[u].z + a4[u].w*e4[u].w;
    }
#pragma unroll
    for (int m = 1; m < 4; m <<= 1) {
      a2 += __shfl_xor(a2, m);
      e2 += __shfl_xor(e2, m);
      ae += __shfl_xor(ae, m);
    }
    const float rna = rsqrtf(a2), rne = rsqrtf(e2);

    // argmax over 7 classes: 2 classes/thread then 4-lane first-max vote
    float pv = pv0; int bi = j4;
    if (pv1 > pv0) { pv = pv1; bi = j4 + 4; }
#pragma unroll
    for (int m = 1; m < 4; m <<= 1) {
      const float ov = __shfl_xor(pv, m);
      const int   oi = __shfl_xor(bi, m);
      if (ov > pv || (ov == pv && oi < bi)) { pv = ov; bi = oi; }
    }

    // positive-sum via precomputed class sums (fp32-exact)
    const float* qs = (const float*)(ws + QSUM_OFF) + bi * 128 + j4 * 32;
    float pdot = 0.f;
#pragma unroll
    for (int u = 0; u < 8; ++u) {
      const float4 qv = *(const float4*)(qs + 4 * u);
      pdot += a4[u].x*qv.x + a4[u].y*qv.y + a4[u].z*qv.z + a4[u].w*qv.w;
    }
#pragma unroll
    for (int m = 1; m < 4; m <<= 1) pdot += __shfl_xor(pdot, m);

    if (j4 == 0) {
      s_lpos[r] = ae * rna * rne * C2L;
      s_pd[r]   = pdot * rna;
    }

    // stage A in MX frag layout: set st = r>>4, target lane tl = j4*16 + (r&15)
    const float sc = rna * C2L;     // pre-scale so MFMA output is 2s/ln2
    const int st = r >> 4, tl = j4 * 16 + (r & 15);
    uint4 w0, w1;
    w0.x = pk8(a4[0].x*sc, a4[0].y*sc, a4[0].z*sc, a4[0].w*sc);
    w0.y = pk8(a4[1].x*sc, a4[1].y*sc, a4[1].z*sc, a4[1].w*sc);
    w0.z = pk8(a4[2].x*sc, a4[2].y*sc, a4[2].z*sc, a4[2].w*sc);
    w0.w = pk8(a4[3].x*sc, a4[3].y*sc, a4[3].z*sc, a4[3].w*sc);
    w1.x = pk8(a4[4].x*sc, a4[4].y*sc, a4[4].z*sc, a4[4].w*sc);
    w1.y = pk8(a4[5].x*sc, a4[5].y*sc, a4[5].z*sc, a4[5].w*sc);
    w1.z = pk8(a4[6].x*sc, a4[6].y*sc, a4[6].z*sc, a4[6].w*sc);
    w1.w = pk8(a4[7].x*sc, a4[7].y*sc, a4[7].z*sc, a4[7].w*sc);
    *(uint4*)(aT + st * 2048 + tl * 32)      = w0;
    *(uint4*)(aT + st * 2048 + tl * 32 + 16) = w1;
  }
  __syncthreads();

  // A fragments: 4 sets (64 rows) per wave, 32 B/lane each (K=128 operand)
  i32x8 sa[4];
#pragma unroll
  for (int s = 0; s < 4; ++s)
    sa[s] = *(const i32x8*)(aT + s * 2048 + lane * 32);

  float dn[4][4] = {{0.f,0.f,0.f,0.f},{0.f,0.f,0.f,0.f},
                    {0.f,0.f,0.f,0.f},{0.f,0.f,0.f,0.f}};
  const f32x4 Z = {0.f, 0.f, 0.f, 0.f};
  const char* qp = ws + (size_t)(wave * GPW) * 2048 + (size_t)lane * 32;
  const int base = blockIdx.x % GPW;   // ONLY delta vs R22: rotated sweep start

  i32x8 B0, B1, B2;
#define LOADG(X, G)                                                     \
  { int gi_ = (G) + base; if (gi_ >= GPW) gi_ -= GPW;                   \
    X = *(const i32x8*)(qp + gi_ * 2048); }
  // 4 independent single MFMAs (K=128 covers all of D), then 16 exps.
#define COMPG(X)                                                        \
  { _Pragma("unroll")                                                   \
    for (int s = 0; s < 4; ++s) {                                       \
      f32x4 c = __builtin_amdgcn_mfma_scale_f32_16x16x128_f8f6f4(       \
          sa[s], X, Z, 0, 0, 0, USCALE, 0, USCALE);                     \
      _Pragma("unroll")                                                 \
      for (int rg = 0; rg < 4; ++rg) dn[s][rg] += fexp2(c[rg]);         \
    } }

  LOADG(B0, 0)
  LOADG(B1, 1)
  LOADG(B2, 2)
#pragma unroll 1
  for (int g = 0; g < GPW - 3; g += 3) {
    COMPG(B0) LOADG(B0, g + 3)
    COMPG(B1) LOADG(B1, g + 4)
    COMPG(B2) LOADG(B2, g + 5)
  }
  COMPG(B0)
  COMPG(B1)
  COMPG(B2)
#undef LOADG
#undef COMPG

  // reduce across the 16 q-column lanes of each row
#pragma unroll
  for (int s = 0; s < 4; ++s)
#pragma unroll
    for (int rg = 0; rg < 4; ++rg)
#pragma unroll
      for (int m = 1; m < 16; m <<= 1)
        dn[s][rg] += __shfl_xor(dn[s][rg], m);

  if (lo == 0) {
#pragma unroll
    for (int s = 0; s < 4; ++s)
#pragma unroll
      for (int rg = 0; rg < 4; ++rg)
        dnp[wave][s * 16 + hi * 4 + rg] = dn[s][rg];
  }
  __syncthreads();

  // epilogue: thread i (< 64) owns block-row i; partial -> plain store
  if (tid < 64) {
    const int i = tid;
    const float dtot = dnp[0][i] + dnp[1][i] + dnp[2][i] + dnp[3][i];
    const float lp   = exp2f(s_lpos[i]);        // exp(2*<f,ema_f>)
    const float dnf  = lp + dtot - (float)NPAD;
    float loss = -logf(lp / dnf + 1e-8f) + 150.0f * logf(dnf) - 2.0f * s_pd[i];
#pragma unroll
    for (int m = 1; m < 64; m <<= 1) loss += __shfl_xor(loss, m);
    if (tid == 0)
      ((float*)(ws + PART_OFF))[blockIdx.x] = loss;   // no atomic
  }
}

// ---- finalize: one block sums the 1024 per-block partials. (verified)
__global__ __launch_bounds__(1024) void finalize(
    const char* __restrict__ ws, float* __restrict__ out)
{
  __shared__ float sred[16];
  const int tid = threadIdx.x;
  float v = ((const float*)(ws + PART_OFF))[tid];
#pragma unroll
  for (int m = 1; m < 64; m <<= 1) v += __shfl_xor(v, m);
  if ((tid & 63) == 0) sred[tid >> 6] = v;
  __syncthreads();
  if (tid < 16) {
    float s = sred[tid];
#pragma unroll
    for (int m = 1; m < 16; m <<= 1) s += __shfl_xor(s, m);
    if (tid == 0) *out = s * (1.0f / (151.0f * 65536.0f));
  }
}

extern "C" void kernel_launch(void* const* d_in, const int* in_sizes, int n_in,
                              void* d_out, int out_size, void* d_ws, size_t ws_size,
                              hipStream_t stream) {
  const float* act   = (const float*)d_in[0];
  const float* ema   = (const float*)d_in[1];
  const float* plab  = (const float*)d_in[2];
  const float* queue = (const float*)d_in[3];
  float* out = (float*)d_out;

  prep_q8<<<dim3(NGRP + CLASS_NUM), dim3(256), 0, stream>>>(queue, (char*)d_ws);

  pgc_stream<<<dim3(NBLK), dim3(256), 0, stream>>>(act, ema, plab, (char*)d_ws);

  finalize<<<dim3(1), dim3(1024), 0, stream>>>((const char*)d_ws, out);
}